// Round 9
// baseline (3672.443 us; speedup 1.0000x reference)
//
#include <hip/hip_runtime.h>
#include <cstdint>
#include <cstddef>

#define N_ROWS 131072   // B*T
#define T_LEN 2048
#define B_BATCH 64
#define H_DIM 128
#define GEMM_GRID 1024
#define GEMM_ROWS 128   // rows per gemm block
#define GWND 8          // gemm staging window
#define WND 8           // rnn window (prefetch depth)
#define PWND 4          // probe window
#define T_PROBE 8192    // probe step count (4x T_LEN for top-5 visibility)
#define LOG2E 1.4426950408889634f

typedef _Float16 half2_t __attribute__((ext_vector_type(2)));
typedef _Float16 half4_t __attribute__((ext_vector_type(4)));
typedef int int2_t __attribute__((ext_vector_type(2)));

// DPP cross-lane ops (VALU pipe, no LDS):
__device__ __forceinline__ float dpp_xor1(float x) {
  int i = __float_as_int(x);
  return __int_as_float(__builtin_amdgcn_update_dpp(i, i, 0xB1, 0xF, 0xF, true));
}
__device__ __forceinline__ float dpp_xor2(float x) {
  int i = __float_as_int(x);
  return __int_as_float(__builtin_amdgcn_update_dpp(i, i, 0x4E, 0xF, 0xF, true));
}
__device__ __forceinline__ float dpp_mirror8(float x) {
  int i = __float_as_int(x);
  return __int_as_float(__builtin_amdgcn_update_dpp(i, i, 0x141, 0xF, 0xF, true));
}

// permlane32_swap butterfly sum: lane i ends with x[i] + x[i^32]
__device__ __forceinline__ float permlane32_sum(float x) {
  int i = __float_as_int(x);
  int2_t r = __builtin_amdgcn_permlane32_swap(i, i, false, false);
  return __int_as_float(r.x) + __int_as_float(r.y);
}

__device__ __forceinline__ float sigmoid2_fast(float spp) {
  // y = 1/(1 + 2^spp), spp already scaled by -log2e
  return __builtin_amdgcn_rcpf(1.0f + __builtin_amdgcn_exp2f(spp));
}

// ---------------------------------------------------------------------------
// Kernel 1: Wx = x @ W^T + fused BN column stats, f16 inputs via v_dot2.
// (the round-5 version — previously passed)
// ---------------------------------------------------------------------------
__global__ __launch_bounds__(256) void gemm_bn_kernel(
    const float* __restrict__ x, const float* __restrict__ W,
    float* __restrict__ Wx, float* __restrict__ stats)
{
  const int tid = threadIdx.x;
  const int hq = tid >> 2;           // 0..63
  const int ks = tid & 3;            // 0..3
  const int k0 = ks << 5;            // 32-float k-slice base
  const int h_own = hq + ((ks & 1) << 6);
  const int h_alt = hq + (((ks & 1) ^ 1) << 6);

  half2_t Wh[2][16];
  {
    const float* w0 = W + (size_t)h_own * H_DIM + k0;
    const float* w1 = W + (size_t)h_alt * H_DIM + k0;
#pragma unroll
    for (int i = 0; i < 16; ++i) {
      half2_t a, b;
      a.x = (_Float16)w0[2 * i]; a.y = (_Float16)w0[2 * i + 1];
      b.x = (_Float16)w1[2 * i]; b.y = (_Float16)w1[2 * i + 1];
      Wh[0][i] = a; Wh[1][i] = b;
    }
  }

  __shared__ __align__(16) _Float16 xs[2][GWND][H_DIM];

  const int r0 = blockIdx.x * GEMM_ROWS;
  const int sr = tid >> 5;   // staging row 0..7
  const int c4 = tid & 31;   // staging float4 col

  {
    float4 v = *reinterpret_cast<const float4*>(&x[(size_t)(r0 + sr) * H_DIM + (c4 << 2)]);
    half4_t h; h.x = (_Float16)v.x; h.y = (_Float16)v.y; h.z = (_Float16)v.z; h.w = (_Float16)v.w;
    *reinterpret_cast<half4_t*>(&xs[0][sr][c4 << 2]) = h;
  }
  __syncthreads();

  float sum = 0.f, sq = 0.f;

  for (int wnd = 0; wnd < GEMM_ROWS; wnd += GWND) {
    const int bw = (wnd >> 3) & 1;
    const bool more = (wnd + GWND < GEMM_ROWS);
    float4 sv;
    if (more)
      sv = *reinterpret_cast<const float4*>(
          &x[(size_t)(r0 + wnd + GWND + sr) * H_DIM + (c4 << 2)]);

#pragma unroll
    for (int r = 0; r < GWND; ++r) {
      const uint4* xv = reinterpret_cast<const uint4*>(&xs[bw][r][k0]);
      uint4 q0 = xv[0], q1 = xv[1], q2 = xv[2], q3 = xv[3];
      half2_t xh[16];
      xh[0]  = __builtin_bit_cast(half2_t, q0.x);
      xh[1]  = __builtin_bit_cast(half2_t, q0.y);
      xh[2]  = __builtin_bit_cast(half2_t, q0.z);
      xh[3]  = __builtin_bit_cast(half2_t, q0.w);
      xh[4]  = __builtin_bit_cast(half2_t, q1.x);
      xh[5]  = __builtin_bit_cast(half2_t, q1.y);
      xh[6]  = __builtin_bit_cast(half2_t, q1.z);
      xh[7]  = __builtin_bit_cast(half2_t, q1.w);
      xh[8]  = __builtin_bit_cast(half2_t, q2.x);
      xh[9]  = __builtin_bit_cast(half2_t, q2.y);
      xh[10] = __builtin_bit_cast(half2_t, q2.z);
      xh[11] = __builtin_bit_cast(half2_t, q2.w);
      xh[12] = __builtin_bit_cast(half2_t, q3.x);
      xh[13] = __builtin_bit_cast(half2_t, q3.y);
      xh[14] = __builtin_bit_cast(half2_t, q3.z);
      xh[15] = __builtin_bit_cast(half2_t, q3.w);

      float p0 = 0.f, p1 = 0.f;
#pragma unroll
      for (int i = 0; i < 16; ++i) {
        p0 = __builtin_amdgcn_fdot2(xh[i], Wh[0][i], p0, false);
        p1 = __builtin_amdgcn_fdot2(xh[i], Wh[1][i], p1, false);
      }
      float qq = p0 + dpp_xor1(p1);
      float s = qq + dpp_xor2(qq);
      if (ks < 2) {
        Wx[(size_t)(r0 + wnd + r) * H_DIM + h_own] = s;
        sum += s;
        sq = fmaf(s, s, sq);
      }
    }
    if (more) {
      half4_t h; h.x = (_Float16)sv.x; h.y = (_Float16)sv.y; h.z = (_Float16)sv.z; h.w = (_Float16)sv.w;
      *reinterpret_cast<half4_t*>(&xs[bw ^ 1][sr][c4 << 2]) = h;
    }
    __syncthreads();
  }
  if (ks < 2) {
    atomicAdd(&stats[h_own], sum);
    atomicAdd(&stats[H_DIM + h_own], sq);
  }
}

// ---------------------------------------------------------------------------
__global__ void bn_finalize_kernel(float* ws, const float* __restrict__ gamma,
                                   const float* __restrict__ beta)
{
  const int h = threadIdx.x;
  const float invN = 1.0f / (float)N_ROWS;
  float mean = ws[h] * invN;
  float e2   = ws[H_DIM + h] * invN;
  float var  = e2 - mean * mean;
  float scl  = gamma[h] * rsqrtf(var + 1e-5f);
  ws[2 * H_DIM + h] = scl;
  ws[3 * H_DIM + h] = beta[h] - mean * scl;
}

// ---------------------------------------------------------------------------
// Kernel 3: recurrence (the PROVEN round-4 4-wave version, rnn = 471 us).
// 256 thr (4 waves); f16 y LDS ping-pong; fdot2; select-free 3-stage DPP
// reduce-scatter; per-step raw lgkmcnt(0)+s_barrier.
// ---------------------------------------------------------------------------
__global__ __launch_bounds__(256) void rnn_kernel(
    const float* __restrict__ V, float* __restrict__ out,
    const float* __restrict__ ws)
{
  const int tid = threadIdx.x;
  const int hq = tid >> 3;           // 0..31
  const int l7 = tid & 7;            // lane within 8-group
  const int g  = (l7 & 3) ^ (3 * ((l7 >> 2) & 1));
  const int h_own = hq + (g << 5);
  const bool wr = (tid & 4) == 0;    // lanes l7<4: unique row owners/writers

  half2_t Vh[4][8];
#pragma unroll
  for (int j = 0; j < 4; ++j) {
    const int hrow = hq + (((unsigned)(j ^ g)) << 5);
    const float* vp = V + (size_t)hrow * H_DIM + (l7 << 4);
#pragma unroll
    for (int i = 0; i < 8; ++i) {
      half2_t h;
      h.x = (_Float16)(-LOG2E * vp[2 * i]);
      h.y = (_Float16)(-LOG2E * vp[2 * i + 1]);
      Vh[j][i] = h;
    }
  }
  const float scl2 = ws[2 * H_DIM + h_own] * (-LOG2E);
  const float shf2 = ws[3 * H_DIM + h_own] * (-LOG2E);

  __shared__ __align__(16) _Float16 ylds[2][H_DIM];

  float* outb = out + (size_t)blockIdx.x * T_LEN * H_DIM;

  if (tid < H_DIM) { ylds[0][tid] = (_Float16)0.f; ylds[1][tid] = (_Float16)0.f; }

  float wxp[WND];
  if (wr) {
#pragma unroll
    for (int u = 0; u < WND; ++u)
      wxp[u] = fmaf(outb[(size_t)u * H_DIM + h_own], scl2, shf2);
  } else {
#pragma unroll
    for (int u = 0; u < WND; ++u) wxp[u] = 0.f;
  }
  __syncthreads();

  float yreg[WND];

  for (int w = 0; w < T_LEN; w += WND) {
    const bool more = (w + WND < T_LEN);
    float wxn[WND];
    if (more && wr) {
#pragma unroll
      for (int u = 0; u < WND; ++u)
        wxn[u] = outb[(size_t)(w + WND + u) * H_DIM + h_own];
    } else {
#pragma unroll
      for (int u = 0; u < WND; ++u) wxn[u] = 0.f;
    }

#pragma unroll
    for (int u = 0; u < WND; ++u) {
      const int t = w + u;
      const uint4* yv = reinterpret_cast<const uint4*>(&ylds[t & 1][l7 << 4]);
      uint4 w0 = yv[0], w1 = yv[1];
      half2_t y2[8];
      y2[0] = __builtin_bit_cast(half2_t, w0.x);
      y2[1] = __builtin_bit_cast(half2_t, w0.y);
      y2[2] = __builtin_bit_cast(half2_t, w0.z);
      y2[3] = __builtin_bit_cast(half2_t, w0.w);
      y2[4] = __builtin_bit_cast(half2_t, w1.x);
      y2[5] = __builtin_bit_cast(half2_t, w1.y);
      y2[6] = __builtin_bit_cast(half2_t, w1.z);
      y2[7] = __builtin_bit_cast(half2_t, w1.w);

      float a0 = 0.f, a1 = 0.f, a2 = 0.f, a3 = 0.f;
#pragma unroll
      for (int i = 0; i < 8; ++i) {
        a0 = __builtin_amdgcn_fdot2(y2[i], Vh[0][i], a0, false);
        a1 = __builtin_amdgcn_fdot2(y2[i], Vh[1][i], a1, false);
        a2 = __builtin_amdgcn_fdot2(y2[i], Vh[2][i], a2, false);
        a3 = __builtin_amdgcn_fdot2(y2[i], Vh[3][i], a3, false);
      }
      float b0 = a0 + dpp_xor1(a1);
      float b1 = a2 + dpp_xor1(a3);
      float c  = b0 + dpp_xor2(b1);
      float red = c + dpp_mirror8(c);
      const float spp = red + wxp[u];
      const float y = sigmoid2_fast(spp);
      if (wr) ylds[(t & 1) ^ 1][h_own] = (_Float16)y;
      yreg[u] = y;
      asm volatile("s_waitcnt lgkmcnt(0)\n\ts_barrier" ::: "memory");
    }

    if (wr) {
#pragma unroll
      for (int u = 0; u < WND; ++u)
        outb[(size_t)(w + u) * H_DIM + h_own] = yreg[u];
    }
#pragma unroll
    for (int u = 0; u < WND; ++u) wxp[u] = fmaf(wxn[u], scl2, shf2);
  }
}

// ---------------------------------------------------------------------------
// PROBE (timing only, no observable writes): correct-work single-wave step.
// Lane (p = l&31, q = l>>5) owns rows 4p..4p+3 x k-half [64q, 64q+64):
// 128 fdot2/lane (full matrix), 1-stage permlane32 butterfly, NO barrier.
// T_PROBE=8192 steps so it tops the dispatch table; per-step = dur/8192.
// Values kept live via asm; LDS single-buffer (same-wave DS is FIFO).
// ---------------------------------------------------------------------------
__global__ __launch_bounds__(64, 1) void probe_1wave(
    const float* __restrict__ V, const float* __restrict__ out,
    const float* __restrict__ ws)
{
  const int lane = threadIdx.x;
  const int p = lane & 31;           // rows 4p..4p+3
  const int q = lane >> 5;           // k-half
  const int kh = q << 6;

  half2_t Vr[4][32];
#pragma unroll
  for (int r = 0; r < 4; ++r) {
    const float* vp = V + (size_t)(4 * p + r) * H_DIM + kh;
#pragma unroll
    for (int i = 0; i < 32; ++i) {
      half2_t h;
      h.x = (_Float16)(-LOG2E * vp[2 * i]);
      h.y = (_Float16)(-LOG2E * vp[2 * i + 1]);
      Vr[r][i] = h;
    }
  }
  float scl[4], shf[4];
#pragma unroll
  for (int r = 0; r < 4; ++r) {
    scl[r] = ws[2 * H_DIM + 4 * p + r] * (-LOG2E);
    shf[r] = ws[3 * H_DIM + 4 * p + r] * (-LOG2E);
  }

  __shared__ __align__(16) _Float16 ylds[H_DIM];
  const float* outb = out + (size_t)blockIdx.x * T_LEN * H_DIM;

  if (lane < 32) {
    half4_t z;
    z.x = (_Float16)0.f; z.y = (_Float16)0.f; z.z = (_Float16)0.f; z.w = (_Float16)0.f;
    *reinterpret_cast<half4_t*>(&ylds[4 * lane]) = z;
  }
  asm volatile("" ::: "memory");

  float4 wxp[PWND];
#pragma unroll
  for (int u = 0; u < PWND; ++u)
    wxp[u] = *reinterpret_cast<const float4*>(&outb[(size_t)u * H_DIM + 4 * p]);

  for (int w = 0; w < T_PROBE; w += PWND) {
    float4 wxn[PWND];
#pragma unroll
    for (int u = 0; u < PWND; ++u) {
      const int wt = (w + PWND + u) & (T_LEN - 1);
      wxn[u] = *reinterpret_cast<const float4*>(&outb[(size_t)wt * H_DIM + 4 * p]);
    }

#pragma unroll
    for (int u = 0; u < PWND; ++u) {
      const uint4* yv = reinterpret_cast<const uint4*>(&ylds[kh]);
      uint4 c0 = yv[0], c1 = yv[1], c2 = yv[2], c3 = yv[3];
      uint4 c4 = yv[4], c5 = yv[5], c6 = yv[6], c7 = yv[7];
      half2_t y2[32];
      {
        uint32_t dw[32] = {c0.x,c0.y,c0.z,c0.w, c1.x,c1.y,c1.z,c1.w,
                           c2.x,c2.y,c2.z,c2.w, c3.x,c3.y,c3.z,c3.w,
                           c4.x,c4.y,c4.z,c4.w, c5.x,c5.y,c5.z,c5.w,
                           c6.x,c6.y,c6.z,c6.w, c7.x,c7.y,c7.z,c7.w};
#pragma unroll
        for (int i = 0; i < 32; ++i) y2[i] = __builtin_bit_cast(half2_t, dw[i]);
      }

      float a0 = 0.f, a1 = 0.f, a2 = 0.f, a3 = 0.f;
#pragma unroll
      for (int i = 0; i < 32; ++i) {
        a0 = __builtin_amdgcn_fdot2(y2[i], Vr[0][i], a0, false);
        a1 = __builtin_amdgcn_fdot2(y2[i], Vr[1][i], a1, false);
        a2 = __builtin_amdgcn_fdot2(y2[i], Vr[2][i], a2, false);
        a3 = __builtin_amdgcn_fdot2(y2[i], Vr[3][i], a3, false);
      }
      const float d0 = permlane32_sum(a0);
      const float d1 = permlane32_sum(a1);
      const float d2 = permlane32_sum(a2);
      const float d3 = permlane32_sum(a3);

      const float yv0 = sigmoid2_fast(fmaf(wxp[u].x, scl[0], shf[0]) + d0);
      const float yv1 = sigmoid2_fast(fmaf(wxp[u].y, scl[1], shf[1]) + d1);
      const float yv2 = sigmoid2_fast(fmaf(wxp[u].z, scl[2], shf[2]) + d2);
      const float yv3 = sigmoid2_fast(fmaf(wxp[u].w, scl[3], shf[3]) + d3);

      if (lane < 32) {
        half4_t h;
        h.x = (_Float16)yv0; h.y = (_Float16)yv1;
        h.z = (_Float16)yv2; h.w = (_Float16)yv3;
        *reinterpret_cast<half4_t*>(&ylds[4 * p]) = h;
      }
      asm volatile("s_waitcnt lgkmcnt(0)" ::: "memory");
      asm volatile("" :: "v"(yv0), "v"(yv1), "v"(yv2), "v"(yv3));
    }
#pragma unroll
    for (int u = 0; u < PWND; ++u) wxp[u] = wxn[u];
  }

  float sink = (float)ylds[lane];
  asm volatile("" :: "v"(sink));
}

// ---------------------------------------------------------------------------
extern "C" void kernel_launch(void* const* d_in, const int* in_sizes, int n_in,
                              void* d_out, int out_size, void* d_ws, size_t ws_size,
                              hipStream_t stream)
{
  (void)in_sizes; (void)n_in; (void)out_size; (void)ws_size;
  const float* x     = (const float*)d_in[0];
  const float* W     = (const float*)d_in[1];
  const float* V     = (const float*)d_in[2];
  const float* gamma = (const float*)d_in[3];
  const float* beta  = (const float*)d_in[4];
  float* out = (float*)d_out;
  float* ws  = (float*)d_ws;

  hipMemsetAsync(ws, 0, 2 * H_DIM * sizeof(float), stream);
  gemm_bn_kernel<<<GEMM_GRID, 256, 0, stream>>>(x, W, out, ws);
  bn_finalize_kernel<<<1, H_DIM, 0, stream>>>(ws, gamma, beta);
  rnn_kernel<<<B_BATCH, 256, 0, stream>>>(V, out, ws);
  // timing probe: reads out/ws, writes nothing observable
  probe_1wave<<<B_BATCH, 64, 0, stream>>>(V, out, ws);
}

// Round 10
// 533.021 us; speedup vs baseline: 6.8899x; 6.8899x over previous
//
#include <hip/hip_runtime.h>
#include <cstdint>
#include <cstddef>

#define N_ROWS 131072   // B*T
#define T_LEN 2048
#define B_BATCH 64
#define H_DIM 128
#define GEMM_GRID 1024
#define GEMM_ROWS 128   // rows per gemm block
#define GWND 8          // gemm staging window
#define WND 8           // rnn window (prefetch depth)
#define LOG2E 1.4426950408889634f

typedef _Float16 half2_t __attribute__((ext_vector_type(2)));
typedef _Float16 half4_t __attribute__((ext_vector_type(4)));

// DPP cross-lane ops (VALU pipe, no LDS):
// quad_perm(1,0,3,2)=0xB1 (xor1), quad_perm(2,3,0,1)=0x4E (xor2),
// ROW_HALF_MIRROR=0x141 (l <-> l^7 within each 8-lane group).
__device__ __forceinline__ float dpp_xor1(float x) {
  int i = __float_as_int(x);
  return __int_as_float(__builtin_amdgcn_update_dpp(i, i, 0xB1, 0xF, 0xF, true));
}
__device__ __forceinline__ float dpp_xor2(float x) {
  int i = __float_as_int(x);
  return __int_as_float(__builtin_amdgcn_update_dpp(i, i, 0x4E, 0xF, 0xF, true));
}
__device__ __forceinline__ float dpp_mirror8(float x) {
  int i = __float_as_int(x);
  return __int_as_float(__builtin_amdgcn_update_dpp(i, i, 0x141, 0xF, 0xF, true));
}

__device__ __forceinline__ float sigmoid2_fast(float spp) {
  // y = 1/(1 + 2^spp), spp already scaled by -log2e
  return __builtin_amdgcn_rcpf(1.0f + __builtin_amdgcn_exp2f(spp));
}

// ---------------------------------------------------------------------------
// Kernel 1: Wx = x @ W^T + fused BN column stats, f16 inputs via v_dot2.
// Lane (hq = tid>>2, ks = tid&3) owns k-slice [32ks,32ks+32) of rows
// {h_own, h_alt}; parity-swapped row order -> select-free 2-stage DPP reduce.
// x rows staged as f16 (converted during staging), double-buffered.
// ---------------------------------------------------------------------------
__global__ __launch_bounds__(256) void gemm_bn_kernel(
    const float* __restrict__ x, const float* __restrict__ W,
    float* __restrict__ Wx, float* __restrict__ stats)
{
  const int tid = threadIdx.x;
  const int hq = tid >> 2;           // 0..63
  const int ks = tid & 3;            // 0..3
  const int k0 = ks << 5;            // 32-float k-slice base
  const int h_own = hq + ((ks & 1) << 6);
  const int h_alt = hq + (((ks & 1) ^ 1) << 6);

  half2_t Wh[2][16];
  {
    const float* w0 = W + (size_t)h_own * H_DIM + k0;
    const float* w1 = W + (size_t)h_alt * H_DIM + k0;
#pragma unroll
    for (int i = 0; i < 16; ++i) {
      half2_t a, b;
      a.x = (_Float16)w0[2 * i]; a.y = (_Float16)w0[2 * i + 1];
      b.x = (_Float16)w1[2 * i]; b.y = (_Float16)w1[2 * i + 1];
      Wh[0][i] = a; Wh[1][i] = b;
    }
  }

  __shared__ __align__(16) _Float16 xs[2][GWND][H_DIM];

  const int r0 = blockIdx.x * GEMM_ROWS;
  const int sr = tid >> 5;   // staging row 0..7
  const int c4 = tid & 31;   // staging float4 col

  {
    float4 v = *reinterpret_cast<const float4*>(&x[(size_t)(r0 + sr) * H_DIM + (c4 << 2)]);
    half4_t h; h.x = (_Float16)v.x; h.y = (_Float16)v.y; h.z = (_Float16)v.z; h.w = (_Float16)v.w;
    *reinterpret_cast<half4_t*>(&xs[0][sr][c4 << 2]) = h;
  }
  __syncthreads();

  float sum = 0.f, sq = 0.f;

  for (int wnd = 0; wnd < GEMM_ROWS; wnd += GWND) {
    const int bw = (wnd >> 3) & 1;
    const bool more = (wnd + GWND < GEMM_ROWS);
    float4 sv;
    if (more)
      sv = *reinterpret_cast<const float4*>(
          &x[(size_t)(r0 + wnd + GWND + sr) * H_DIM + (c4 << 2)]);

#pragma unroll
    for (int r = 0; r < GWND; ++r) {
      const uint4* xv = reinterpret_cast<const uint4*>(&xs[bw][r][k0]);
      uint4 q0 = xv[0], q1 = xv[1], q2 = xv[2], q3 = xv[3];
      half2_t xh[16];
      xh[0]  = __builtin_bit_cast(half2_t, q0.x);
      xh[1]  = __builtin_bit_cast(half2_t, q0.y);
      xh[2]  = __builtin_bit_cast(half2_t, q0.z);
      xh[3]  = __builtin_bit_cast(half2_t, q0.w);
      xh[4]  = __builtin_bit_cast(half2_t, q1.x);
      xh[5]  = __builtin_bit_cast(half2_t, q1.y);
      xh[6]  = __builtin_bit_cast(half2_t, q1.z);
      xh[7]  = __builtin_bit_cast(half2_t, q1.w);
      xh[8]  = __builtin_bit_cast(half2_t, q2.x);
      xh[9]  = __builtin_bit_cast(half2_t, q2.y);
      xh[10] = __builtin_bit_cast(half2_t, q2.z);
      xh[11] = __builtin_bit_cast(half2_t, q2.w);
      xh[12] = __builtin_bit_cast(half2_t, q3.x);
      xh[13] = __builtin_bit_cast(half2_t, q3.y);
      xh[14] = __builtin_bit_cast(half2_t, q3.z);
      xh[15] = __builtin_bit_cast(half2_t, q3.w);

      float p0 = 0.f, p1 = 0.f;
#pragma unroll
      for (int i = 0; i < 16; ++i) {
        p0 = __builtin_amdgcn_fdot2(xh[i], Wh[0][i], p0, false);
        p1 = __builtin_amdgcn_fdot2(xh[i], Wh[1][i], p1, false);
      }
      float qq = p0 + dpp_xor1(p1);
      float s = qq + dpp_xor2(qq);
      if (ks < 2) {
        Wx[(size_t)(r0 + wnd + r) * H_DIM + h_own] = s;
        sum += s;
        sq = fmaf(s, s, sq);
      }
    }
    if (more) {
      half4_t h; h.x = (_Float16)sv.x; h.y = (_Float16)sv.y; h.z = (_Float16)sv.z; h.w = (_Float16)sv.w;
      *reinterpret_cast<half4_t*>(&xs[bw ^ 1][sr][c4 << 2]) = h;
    }
    __syncthreads();
  }
  if (ks < 2) {
    atomicAdd(&stats[h_own], sum);
    atomicAdd(&stats[H_DIM + h_own], sq);
  }
}

// ---------------------------------------------------------------------------
// Kernel 2: fold BN stats into scale/shift
// ---------------------------------------------------------------------------
__global__ void bn_finalize_kernel(float* ws, const float* __restrict__ gamma,
                                   const float* __restrict__ beta)
{
  const int h = threadIdx.x;
  const float invN = 1.0f / (float)N_ROWS;
  float mean = ws[h] * invN;
  float e2   = ws[H_DIM + h] * invN;
  float var  = e2 - mean * mean;
  float scl  = gamma[h] * rsqrtf(var + 1e-5f);
  ws[2 * H_DIM + h] = scl;
  ws[3 * H_DIM + h] = beta[h] - mean * scl;
}

// ---------------------------------------------------------------------------
// Kernel 3: recurrence, in-place on d_out (holds Wx). One block/batch,
// 256 thr (4 waves). f16 y in LDS ping-pong; V as f16 pre-scaled by -log2e
// (exp2-domain sigmoid); per-lane: 4 rows x 16-k slice via v_dot2_f32_f16;
// select-free 3-stage DPP reduce-scatter (xor1, xor2, row_half_mirror).
// Lane l (within 8-group): accumulator j holds row j ^ g, g=(l&3)^(3*(l>>2&1)).
// Per-step sync: raw lgkmcnt(0)+s_barrier (LDS visibility only; global
// loads/stores stay in flight across it). Proven at 471 us (R4/R8).
// Measured plateau: ~552 cyc/step = barrier + LDS round-trip latency+queue +
// 32-fdot2 issue + reduce + sigmoid. Single-wave barrier-free alternative
// measured via R8 probe at 923 cyc/step -> rejected.
// ---------------------------------------------------------------------------
__global__ __launch_bounds__(256) void rnn_kernel(
    const float* __restrict__ V, float* __restrict__ out,
    const float* __restrict__ ws)
{
  const int tid = threadIdx.x;
  const int hq = tid >> 3;           // 0..31
  const int l7 = tid & 7;            // lane within 8-group
  const int g  = (l7 & 3) ^ (3 * ((l7 >> 2) & 1));
  const int h_own = hq + (g << 5);
  const bool wr = (tid & 4) == 0;    // lanes l7<4: unique row owners/writers

  half2_t Vh[4][8];
#pragma unroll
  for (int j = 0; j < 4; ++j) {
    const int hrow = hq + (((unsigned)(j ^ g)) << 5);
    const float* vp = V + (size_t)hrow * H_DIM + (l7 << 4);
#pragma unroll
    for (int i = 0; i < 8; ++i) {
      half2_t h;
      h.x = (_Float16)(-LOG2E * vp[2 * i]);
      h.y = (_Float16)(-LOG2E * vp[2 * i + 1]);
      Vh[j][i] = h;
    }
  }
  const float scl2 = ws[2 * H_DIM + h_own] * (-LOG2E);
  const float shf2 = ws[3 * H_DIM + h_own] * (-LOG2E);

  __shared__ __align__(16) _Float16 ylds[2][H_DIM];

  float* outb = out + (size_t)blockIdx.x * T_LEN * H_DIM;

  if (tid < H_DIM) { ylds[0][tid] = (_Float16)0.f; ylds[1][tid] = (_Float16)0.f; }

  float wxp[WND];
  if (wr) {
#pragma unroll
    for (int u = 0; u < WND; ++u)
      wxp[u] = fmaf(outb[(size_t)u * H_DIM + h_own], scl2, shf2);
  } else {
#pragma unroll
    for (int u = 0; u < WND; ++u) wxp[u] = 0.f;
  }
  __syncthreads();

  float yreg[WND];

  for (int w = 0; w < T_LEN; w += WND) {
    const bool more = (w + WND < T_LEN);
    float wxn[WND];
    if (more && wr) {  // prefetch next window's wx (hides under 8 steps)
#pragma unroll
      for (int u = 0; u < WND; ++u)
        wxn[u] = outb[(size_t)(w + WND + u) * H_DIM + h_own];
    } else {
#pragma unroll
      for (int u = 0; u < WND; ++u) wxn[u] = 0.f;
    }

#pragma unroll
    for (int u = 0; u < WND; ++u) {
      const int t = w + u;
      const uint4* yv = reinterpret_cast<const uint4*>(&ylds[t & 1][l7 << 4]);
      uint4 w0 = yv[0], w1 = yv[1];
      half2_t y2[8];
      y2[0] = __builtin_bit_cast(half2_t, w0.x);
      y2[1] = __builtin_bit_cast(half2_t, w0.y);
      y2[2] = __builtin_bit_cast(half2_t, w0.z);
      y2[3] = __builtin_bit_cast(half2_t, w0.w);
      y2[4] = __builtin_bit_cast(half2_t, w1.x);
      y2[5] = __builtin_bit_cast(half2_t, w1.y);
      y2[6] = __builtin_bit_cast(half2_t, w1.z);
      y2[7] = __builtin_bit_cast(half2_t, w1.w);

      float a0 = 0.f, a1 = 0.f, a2 = 0.f, a3 = 0.f;
#pragma unroll
      for (int i = 0; i < 8; ++i) {
        a0 = __builtin_amdgcn_fdot2(y2[i], Vh[0][i], a0, false);
        a1 = __builtin_amdgcn_fdot2(y2[i], Vh[1][i], a1, false);
        a2 = __builtin_amdgcn_fdot2(y2[i], Vh[2][i], a2, false);
        a3 = __builtin_amdgcn_fdot2(y2[i], Vh[3][i], a3, false);
      }
      float b0 = a0 + dpp_xor1(a1);
      float b1 = a2 + dpp_xor1(a3);
      float c  = b0 + dpp_xor2(b1);
      float red = c + dpp_mirror8(c);
      const float spp = red + wxp[u];
      const float y = sigmoid2_fast(spp);
      if (wr) ylds[(t & 1) ^ 1][h_own] = (_Float16)y;
      yreg[u] = y;
      // LDS visibility only; global loads/stores stay in flight.
      asm volatile("s_waitcnt lgkmcnt(0)\n\ts_barrier" ::: "memory");
    }

    if (wr) {  // flush window outputs (overwrites consumed Wx)
#pragma unroll
      for (int u = 0; u < WND; ++u)
        outb[(size_t)(w + u) * H_DIM + h_own] = yreg[u];
    }
#pragma unroll
    for (int u = 0; u < WND; ++u) wxp[u] = fmaf(wxn[u], scl2, shf2);
  }
}

// ---------------------------------------------------------------------------
extern "C" void kernel_launch(void* const* d_in, const int* in_sizes, int n_in,
                              void* d_out, int out_size, void* d_ws, size_t ws_size,
                              hipStream_t stream)
{
  (void)in_sizes; (void)n_in; (void)out_size; (void)ws_size;
  const float* x     = (const float*)d_in[0];
  const float* W     = (const float*)d_in[1];
  const float* V     = (const float*)d_in[2];
  const float* gamma = (const float*)d_in[3];
  const float* beta  = (const float*)d_in[4];
  float* out = (float*)d_out;
  float* ws  = (float*)d_ws;

  hipMemsetAsync(ws, 0, 2 * H_DIM * sizeof(float), stream);
  gemm_bn_kernel<<<GEMM_GRID, 256, 0, stream>>>(x, W, out, ws);
  bn_finalize_kernel<<<1, H_DIM, 0, stream>>>(ws, gamma, beta);
  rnn_kernel<<<B_BATCH, 256, 0, stream>>>(V, out, ws);
}

// Round 11
// 519.222 us; speedup vs baseline: 7.0730x; 1.0266x over previous
//
#include <hip/hip_runtime.h>
#include <cstdint>
#include <cstddef>

#define N_ROWS 131072   // B*T
#define T_LEN 2048
#define B_BATCH 64
#define H_DIM 128
#define GEMM_GRID 1024  // 128 rows per block
#define WND 8           // rnn window (prefetch depth)
#define LOG2E 1.4426950408889634f

typedef _Float16 half2_t __attribute__((ext_vector_type(2)));
typedef _Float16 half8_t __attribute__((ext_vector_type(8)));
typedef float f32x4_t __attribute__((ext_vector_type(4)));
typedef int int2_t __attribute__((ext_vector_type(2)));

// DPP cross-lane ops (VALU pipe, no LDS) — used by the rnn reduce-scatter.
__device__ __forceinline__ float dpp_xor1(float x) {
  int i = __float_as_int(x);
  return __int_as_float(__builtin_amdgcn_update_dpp(i, i, 0xB1, 0xF, 0xF, true));
}
__device__ __forceinline__ float dpp_xor2(float x) {
  int i = __float_as_int(x);
  return __int_as_float(__builtin_amdgcn_update_dpp(i, i, 0x4E, 0xF, 0xF, true));
}
__device__ __forceinline__ float dpp_mirror8(float x) {
  int i = __float_as_int(x);
  return __int_as_float(__builtin_amdgcn_update_dpp(i, i, 0x141, 0xF, 0xF, true));
}

// permlaneN_swap butterfly sum: lane i ends with x[i] + x[i^N].
// (vdst gets src's low half into its high half and vice versa; with both
// inputs = x the pair sums to the partner-sum in every lane.)
__device__ __forceinline__ float permlane16_sum(float x) {
  int i = __float_as_int(x);
  int2_t r = __builtin_amdgcn_permlane16_swap(i, i, false, false);
  return __int_as_float(r.x) + __int_as_float(r.y);
}
__device__ __forceinline__ float permlane32_sum(float x) {
  int i = __float_as_int(x);
  int2_t r = __builtin_amdgcn_permlane32_swap(i, i, false, false);
  return __int_as_float(r.x) + __int_as_float(r.y);
}

__device__ __forceinline__ float sigmoid2_fast(float spp) {
  // y = 1/(1 + 2^spp), spp already scaled by -log2e
  return __builtin_amdgcn_rcpf(1.0f + __builtin_amdgcn_exp2f(spp));
}

// ---------------------------------------------------------------------------
// Kernel 1: Wx = x @ W^T + fused BN column stats — MFMA version.
// Per block: 128x128 output tile. 4 waves; wave wv owns 32 cols (2 N-tiles),
// B-frags (W cols, f16) held in regs. x tile staged once to LDS as f16 with
// XOR swizzle (byte ^= (row&7)<<4 on 16B chunks) -> A-frag ds_read_b128 is
// 2-lanes/slot (free). C/D layout (m89-verified): col=lane&15,
// row=(lane>>4)*4+reg -> 64B-coalesced stores. Stats: per-lane col partials,
// permlane16+32 butterfly over the 4 row-groups, 1 atomic/col/block.
// ---------------------------------------------------------------------------
__global__ __launch_bounds__(256) void gemm_bn_kernel(
    const float* __restrict__ x, const float* __restrict__ W,
    float* __restrict__ Wx, float* __restrict__ stats)
{
  const int tid  = threadIdx.x;
  const int lane = tid & 63;
  const int wv   = tid >> 6;        // wave 0..3
  const int l15  = lane & 15;
  const int kg   = lane >> 4;       // k-group 0..3
  const int r0   = blockIdx.x * 128;

  // B fragments: col = wv*32 + n*16 + l15, k = k*32 + kg*8 .. +8
  half8_t Bf[2][4];
#pragma unroll
  for (int n = 0; n < 2; ++n) {
    const int col = wv * 32 + n * 16 + l15;
    const float* wp = W + (size_t)col * H_DIM;
#pragma unroll
    for (int k = 0; k < 4; ++k) {
      const float* w8 = wp + k * 32 + kg * 8;
      half8_t b;
#pragma unroll
      for (int i = 0; i < 8; ++i) b[i] = (_Float16)w8[i];
      Bf[n][k] = b;
    }
  }

  // Stage x tile (128 rows x 128 f32 -> f16) into LDS, swizzled.
  __shared__ __align__(16) _Float16 xs[128 * 128];
  {
    const int row = tid >> 1;
    const int hf  = tid & 1;         // half-row (64 floats)
    const float* xp = x + (size_t)(r0 + row) * H_DIM + hf * 64;
    const int swz = (row & 7) << 4;
    char* base = reinterpret_cast<char*>(xs) + row * 256;
#pragma unroll
    for (int c = 0; c < 8; ++c) {
      float4 v0 = *reinterpret_cast<const float4*>(xp + c * 8);
      float4 v1 = *reinterpret_cast<const float4*>(xp + c * 8 + 4);
      half8_t h;
      h[0] = (_Float16)v0.x; h[1] = (_Float16)v0.y;
      h[2] = (_Float16)v0.z; h[3] = (_Float16)v0.w;
      h[4] = (_Float16)v1.x; h[5] = (_Float16)v1.y;
      h[6] = (_Float16)v1.z; h[7] = (_Float16)v1.w;
      const int X = hf * 128 + c * 16;   // byte offset within the 256B row
      *reinterpret_cast<half8_t*>(base + (X ^ swz)) = h;
    }
  }
  __syncthreads();

  f32x4_t C[8][2];
#pragma unroll
  for (int m = 0; m < 8; ++m)
#pragma unroll
    for (int n = 0; n < 2; ++n)
      C[m][n] = (f32x4_t){0.f, 0.f, 0.f, 0.f};

#pragma unroll
  for (int m = 0; m < 8; ++m) {
    const int row = m * 16 + l15;                 // A-frag row
    const char* rbase = reinterpret_cast<const char*>(xs) + row * 256;
    const int swz = (row & 7) << 4;
#pragma unroll
    for (int k = 0; k < 4; ++k) {
      const int X = k * 64 + kg * 16;             // k*32 halves + kg*8 halves
      half8_t a = *reinterpret_cast<const half8_t*>(rbase + (X ^ swz));
      C[m][0] = __builtin_amdgcn_mfma_f32_16x16x32_f16(a, Bf[0][k], C[m][0], 0, 0, 0);
      C[m][1] = __builtin_amdgcn_mfma_f32_16x16x32_f16(a, Bf[1][k], C[m][1], 0, 0, 0);
    }
  }

  // Epilogue: store (coalesced 64B per 16 lanes) + column stat partials.
  float sum0 = 0.f, sq0 = 0.f, sum1 = 0.f, sq1 = 0.f;
#pragma unroll
  for (int m = 0; m < 8; ++m) {
#pragma unroll
    for (int j = 0; j < 4; ++j) {
      const int row = r0 + m * 16 + kg * 4 + j;
      const float v0 = C[m][0][j];
      const float v1 = C[m][1][j];
      Wx[(size_t)row * H_DIM + wv * 32 + l15]      = v0;
      Wx[(size_t)row * H_DIM + wv * 32 + 16 + l15] = v1;
      sum0 += v0; sq0 = fmaf(v0, v0, sq0);
      sum1 += v1; sq1 = fmaf(v1, v1, sq1);
    }
  }
  // butterfly over lanes {l15, l15^16, l15^32, l15^48} = the 4 kg row-groups
  float s0 = permlane32_sum(permlane16_sum(sum0));
  float q0 = permlane32_sum(permlane16_sum(sq0));
  float s1 = permlane32_sum(permlane16_sum(sum1));
  float q1 = permlane32_sum(permlane16_sum(sq1));
  if (lane < 16) {
    atomicAdd(&stats[wv * 32 + lane],              s0);
    atomicAdd(&stats[H_DIM + wv * 32 + lane],      q0);
    atomicAdd(&stats[wv * 32 + 16 + lane],         s1);
    atomicAdd(&stats[H_DIM + wv * 32 + 16 + lane], q1);
  }
}

// ---------------------------------------------------------------------------
// Kernel 2: fold BN stats into scale/shift
// ---------------------------------------------------------------------------
__global__ void bn_finalize_kernel(float* ws, const float* __restrict__ gamma,
                                   const float* __restrict__ beta)
{
  const int h = threadIdx.x;
  const float invN = 1.0f / (float)N_ROWS;
  float mean = ws[h] * invN;
  float e2   = ws[H_DIM + h] * invN;
  float var  = e2 - mean * mean;
  float scl  = gamma[h] * rsqrtf(var + 1e-5f);
  ws[2 * H_DIM + h] = scl;
  ws[3 * H_DIM + h] = beta[h] - mean * scl;
}

// ---------------------------------------------------------------------------
// Kernel 3: recurrence — VERBATIM the proven R4/R8/R10 kernel (471 us).
// Measured plateau ~552 cyc/step (structural: barrier + LDS round-trip +
// fdot2 issue + sigmoid); 1-wave (923) and 16-wave (1412) alternatives
// measured and rejected.
// ---------------------------------------------------------------------------
__global__ __launch_bounds__(256) void rnn_kernel(
    const float* __restrict__ V, float* __restrict__ out,
    const float* __restrict__ ws)
{
  const int tid = threadIdx.x;
  const int hq = tid >> 3;           // 0..31
  const int l7 = tid & 7;            // lane within 8-group
  const int g  = (l7 & 3) ^ (3 * ((l7 >> 2) & 1));
  const int h_own = hq + (g << 5);
  const bool wr = (tid & 4) == 0;    // lanes l7<4: unique row owners/writers

  half2_t Vh[4][8];
#pragma unroll
  for (int j = 0; j < 4; ++j) {
    const int hrow = hq + (((unsigned)(j ^ g)) << 5);
    const float* vp = V + (size_t)hrow * H_DIM + (l7 << 4);
#pragma unroll
    for (int i = 0; i < 8; ++i) {
      half2_t h;
      h.x = (_Float16)(-LOG2E * vp[2 * i]);
      h.y = (_Float16)(-LOG2E * vp[2 * i + 1]);
      Vh[j][i] = h;
    }
  }
  const float scl2 = ws[2 * H_DIM + h_own] * (-LOG2E);
  const float shf2 = ws[3 * H_DIM + h_own] * (-LOG2E);

  __shared__ __align__(16) _Float16 ylds[2][H_DIM];

  float* outb = out + (size_t)blockIdx.x * T_LEN * H_DIM;

  if (tid < H_DIM) { ylds[0][tid] = (_Float16)0.f; ylds[1][tid] = (_Float16)0.f; }

  float wxp[WND];
  if (wr) {
#pragma unroll
    for (int u = 0; u < WND; ++u)
      wxp[u] = fmaf(outb[(size_t)u * H_DIM + h_own], scl2, shf2);
  } else {
#pragma unroll
    for (int u = 0; u < WND; ++u) wxp[u] = 0.f;
  }
  __syncthreads();

  float yreg[WND];

  for (int w = 0; w < T_LEN; w += WND) {
    const bool more = (w + WND < T_LEN);
    float wxn[WND];
    if (more && wr) {  // prefetch next window's wx (hides under 8 steps)
#pragma unroll
      for (int u = 0; u < WND; ++u)
        wxn[u] = outb[(size_t)(w + WND + u) * H_DIM + h_own];
    } else {
#pragma unroll
      for (int u = 0; u < WND; ++u) wxn[u] = 0.f;
    }

#pragma unroll
    for (int u = 0; u < WND; ++u) {
      const int t = w + u;
      const uint4* yv = reinterpret_cast<const uint4*>(&ylds[t & 1][l7 << 4]);
      uint4 w0 = yv[0], w1 = yv[1];
      half2_t y2[8];
      y2[0] = __builtin_bit_cast(half2_t, w0.x);
      y2[1] = __builtin_bit_cast(half2_t, w0.y);
      y2[2] = __builtin_bit_cast(half2_t, w0.z);
      y2[3] = __builtin_bit_cast(half2_t, w0.w);
      y2[4] = __builtin_bit_cast(half2_t, w1.x);
      y2[5] = __builtin_bit_cast(half2_t, w1.y);
      y2[6] = __builtin_bit_cast(half2_t, w1.z);
      y2[7] = __builtin_bit_cast(half2_t, w1.w);

      float a0 = 0.f, a1 = 0.f, a2 = 0.f, a3 = 0.f;
#pragma unroll
      for (int i = 0; i < 8; ++i) {
        a0 = __builtin_amdgcn_fdot2(y2[i], Vh[0][i], a0, false);
        a1 = __builtin_amdgcn_fdot2(y2[i], Vh[1][i], a1, false);
        a2 = __builtin_amdgcn_fdot2(y2[i], Vh[2][i], a2, false);
        a3 = __builtin_amdgcn_fdot2(y2[i], Vh[3][i], a3, false);
      }
      float b0 = a0 + dpp_xor1(a1);
      float b1 = a2 + dpp_xor1(a3);
      float c  = b0 + dpp_xor2(b1);
      float red = c + dpp_mirror8(c);
      const float spp = red + wxp[u];
      const float y = sigmoid2_fast(spp);
      if (wr) ylds[(t & 1) ^ 1][h_own] = (_Float16)y;
      yreg[u] = y;
      // LDS visibility only; global loads/stores stay in flight.
      asm volatile("s_waitcnt lgkmcnt(0)\n\ts_barrier" ::: "memory");
    }

    if (wr) {  // flush window outputs (overwrites consumed Wx)
#pragma unroll
      for (int u = 0; u < WND; ++u)
        outb[(size_t)(w + u) * H_DIM + h_own] = yreg[u];
    }
#pragma unroll
    for (int u = 0; u < WND; ++u) wxp[u] = fmaf(wxn[u], scl2, shf2);
  }
}

// ---------------------------------------------------------------------------
extern "C" void kernel_launch(void* const* d_in, const int* in_sizes, int n_in,
                              void* d_out, int out_size, void* d_ws, size_t ws_size,
                              hipStream_t stream)
{
  (void)in_sizes; (void)n_in; (void)out_size; (void)ws_size;
  const float* x     = (const float*)d_in[0];
  const float* W     = (const float*)d_in[1];
  const float* V     = (const float*)d_in[2];
  const float* gamma = (const float*)d_in[3];
  const float* beta  = (const float*)d_in[4];
  float* out = (float*)d_out;
  float* ws  = (float*)d_ws;

  hipMemsetAsync(ws, 0, 2 * H_DIM * sizeof(float), stream);
  gemm_bn_kernel<<<GEMM_GRID, 256, 0, stream>>>(x, W, out, ws);
  bn_finalize_kernel<<<1, H_DIM, 0, stream>>>(ws, gamma, beta);
  rnn_kernel<<<B_BATCH, 256, 0, stream>>>(V, out, ws);
}